// Round 4
// baseline (398.979 us; speedup 1.0000x reference)
//
#include <hip/hip_runtime.h>
#include <hip/hip_bf16.h>
#include <hip/hip_fp16.h>

#define NN 8192
#define NROWS 4096            // B*C = 64*64
#define KSPLIT 8
#define KCHUNK (NN / KSPLIT)  // 1024
static constexpr float TWO_PI = 6.28318530717958647692f;

typedef __attribute__((ext_vector_type(8))) _Float16 half8;
typedef __attribute__((ext_vector_type(4))) float floatx4;

// ---------------- twiddle generation (all on-device, every launch) -------------
// btF[j][k], j in [0,128): j<64 -> cos(2pi j k/N); j>=64 -> -sin(2pi (j-64) k/N)
__global__ __launch_bounds__(256) void gen_fwd(_Float16* __restrict__ bt) {
    const int idx = blockIdx.x * 256 + threadIdx.x;   // 128*8192 = 1M threads
    const int j = idx >> 13;
    const int k = idx & (NN - 1);
    const int m = j & 63;
    const int t = (m * k) & (NN - 1);                 // exact mod-N reduction
    float s, c;
    sincosf((float)t * (TWO_PI / (float)NN), &s, &c);
    bt[idx] = (_Float16)((j < 64) ? c : -s);
}

// gt[n][c], c in [0,128): c<64 -> cos(2pi c n/N); c>=64 -> sin(2pi (c-64) n/N)
__global__ __launch_bounds__(256) void gen_inv(_Float16* __restrict__ gt) {
    const int idx = blockIdx.x * 256 + threadIdx.x;   // 8192*128 = 1M threads
    const int n = idx >> 7;
    const int c = idx & 127;
    const int m = c & 63;
    const int t = (m * n) & (NN - 1);
    float s, cc;
    sincosf((float)t * (TWO_PI / (float)NN), &s, &cc);
    gt[idx] = (_Float16)((c < 64) ? cc : s);
}

static __device__ inline half8 cvt8(float4 a, float4 b) {
    half8 h;
    h[0] = (_Float16)a.x; h[1] = (_Float16)a.y; h[2] = (_Float16)a.z; h[3] = (_Float16)a.w;
    h[4] = (_Float16)b.x; h[5] = (_Float16)b.y; h[6] = (_Float16)b.z; h[7] = (_Float16)b.w;
    return h;
}

// ---------------- GEMM1: Vhat_partial = v x btF^T --------------------------------
// grid = 256 Mtiles(16 rows) x 8 K-splits = 2048 blocks (8/CU). 4 waves per block
// split the 128 j-columns (32 each) -> no LDS, no cross-wave reduce. Inner loop
// prefetches 128 K-elements (8 float4 A + 8 half8 B) into regs before the MFMAs
// so ~16 loads/wave stay in flight (Little's law: need KBs in flight per CU).
__global__ __launch_bounds__(256) void gemm_fwd(const float* __restrict__ v,
                                                const _Float16* __restrict__ bt,
                                                float* __restrict__ part) {
    const int wid   = threadIdx.x >> 6;        // 0..3 -> j-quarter
    const int lane  = threadIdx.x & 63;
    const int l15   = lane & 15;
    const int g     = lane >> 4;               // 0..3 (k-subgroup)
    const int s     = blockIdx.x & (KSPLIT - 1);
    const int mtile = blockIdx.x >> 3;         // 0..255

    const int rowA = mtile * 16 + l15;
    const int k0   = s * KCHUNK + g * 8;
    const float*    ap  = v + (size_t)rowA * NN + k0;
    const int j0 = wid * 32;
    const _Float16* bp0 = bt + (size_t)(j0 + l15) * NN + k0;
    const _Float16* bp1 = bt + (size_t)(j0 + 16 + l15) * NN + k0;

    floatx4 acc0 = {}, acc1 = {};
    for (int kk = 0; kk < KCHUNK; kk += 128) {
        float4 a[8];
        half8 b0[4], b1[4];
        #pragma unroll
        for (int t = 0; t < 4; ++t) {
            a[2 * t]     = *(const float4*)(ap + kk + t * 32);
            a[2 * t + 1] = *(const float4*)(ap + kk + t * 32 + 4);
            b0[t] = *(const half8*)(bp0 + kk + t * 32);
            b1[t] = *(const half8*)(bp1 + kk + t * 32);
        }
        #pragma unroll
        for (int t = 0; t < 4; ++t) {
            half8 af = cvt8(a[2 * t], a[2 * t + 1]);
            acc0 = __builtin_amdgcn_mfma_f32_16x16x32_f16(af, b0[t], acc0, 0, 0, 0);
            acc1 = __builtin_amdgcn_mfma_f32_16x16x32_f16(af, b1[t], acc1, 0, 0, 0);
        }
    }

    float* pout = part + (size_t)s * NROWS * 128
                + (size_t)(mtile * 16 + g * 4) * 128 + j0 + l15;
    #pragma unroll
    for (int r = 0; r < 4; ++r) {
        pout[(size_t)r * 128]      = acc0[r];
        pout[(size_t)r * 128 + 16] = acc1[r];
    }
}

// ---------------- reduce K-split partials ----------------------------------------
__global__ __launch_bounds__(256) void reduce_part(const float* __restrict__ part,
                                                   float* __restrict__ vhat) {
    const int idx = blockIdx.x * 256 + threadIdx.x;    // 4096*128 = 512K
    float a = 0.f;
    #pragma unroll
    for (int s = 0; s < KSPLIT; ++s) a += part[(size_t)s * NROWS * 128 + idx];
    vhat[idx] = a;
}

// ---------------- mix: per-frequency complex channel mix + irfft scaling --------
// Xc[row][m] = 2/N * Re(Xhat) (m=0: 1/N), Xc[row][64+m] = -2/N * Im(Xhat)
__global__ __launch_bounds__(256) void mix(const float* __restrict__ vhat,
                                           const float* __restrict__ wr,
                                           const float* __restrict__ wi,
                                           _Float16* __restrict__ xc) {
    const int m  = threadIdx.x & 63;
    const int ol = threadIdx.x >> 6;
    const int b  = blockIdx.x >> 4;
    const int o  = ((blockIdx.x & 15) << 2) + ol;

    float ar = 0.f, ai = 0.f;
    #pragma unroll 4
    for (int i = 0; i < 64; ++i) {
        const float* vrow = vhat + (size_t)(b * 64 + i) * 128;
        const float vr = vrow[m];
        const float vi = vrow[64 + m];
        const float wre = wr[((size_t)(i * 64 + o)) * 64 + m];
        const float wim = wi[((size_t)(i * 64 + o)) * 64 + m];
        ar = fmaf(vr, wre, ar);  ar = fmaf(-vi, wim, ar);
        ai = fmaf(vr, wim, ai);  ai = fmaf(vi, wre, ai);
    }
    _Float16* xrow = xc + (size_t)(b * 64 + o) * 128;
    if (m == 0) {
        xrow[0]  = (_Float16)(ar * (1.f / (float)NN));
        xrow[64] = (_Float16)0.f;
    } else {
        xrow[m]      = (_Float16)(ar * (2.f / (float)NN));
        xrow[64 + m] = (_Float16)(-ai * (2.f / (float)NN));
    }
}

// ---------------- GEMM2: out = Xc (4096x128) x G (128x8192) ---------------------
// grid = 256 row-tiles x 32 col-tiles; wave owns 16 rows x 64 cols, K=128.
__global__ __launch_bounds__(256) void gemm_inv(const _Float16* __restrict__ xc,
                                                const _Float16* __restrict__ gt,
                                                float* __restrict__ out) {
    const int wid  = threadIdx.x >> 6;
    const int lane = threadIdx.x & 63;
    const int l15  = lane & 15;
    const int g    = lane >> 4;
    const int mt   = blockIdx.x >> 5;
    const int nt   = blockIdx.x & 31;
    const int row0 = mt * 16;
    const int col0 = nt * 256 + wid * 64;

    half8 af[4];
    const _Float16* ap = xc + (size_t)(row0 + l15) * 128 + g * 8;
    #pragma unroll
    for (int ks = 0; ks < 4; ++ks) af[ks] = *(const half8*)(ap + ks * 32);

    floatx4 acc[4] = {};
    #pragma unroll
    for (int jt = 0; jt < 4; ++jt) {
        const _Float16* gp = gt + (size_t)(col0 + jt * 16 + l15) * 128 + g * 8;
        #pragma unroll
        for (int ks = 0; ks < 4; ++ks) {
            half8 bf = *(const half8*)(gp + ks * 32);
            acc[jt] = __builtin_amdgcn_mfma_f32_16x16x32_f16(af[ks], bf, acc[jt], 0, 0, 0);
        }
    }

    #pragma unroll
    for (int jt = 0; jt < 4; ++jt)
        #pragma unroll
        for (int r = 0; r < 4; ++r)
            out[(size_t)(row0 + g * 4 + r) * NN + col0 + jt * 16 + l15] = acc[jt][r];
}

extern "C" void kernel_launch(void* const* d_in, const int* in_sizes, int n_in,
                              void* d_out, int out_size, void* d_ws, size_t ws_size,
                              hipStream_t stream) {
    const float* v  = (const float*)d_in[0];
    const float* wr = (const float*)d_in[1];
    const float* wi = (const float*)d_in[2];
    float* out = (float*)d_out;

    char* ws = (char*)d_ws;
    _Float16* btF  = (_Float16*)(ws);                               // 2 MiB
    _Float16* gt   = (_Float16*)(ws + (2u << 20));                  // 2 MiB
    float*    part = (float*)   (ws + (4u << 20));                  // 16 MiB
    float*    vhat = (float*)   (ws + (20u << 20));                 // 2 MiB
    _Float16* xc   = (_Float16*)(ws + (22u << 20));                 // 1 MiB

    gen_fwd<<<4096, 256, 0, stream>>>(btF);
    gen_inv<<<4096, 256, 0, stream>>>(gt);
    gemm_fwd<<<256 * KSPLIT, 256, 0, stream>>>(v, btF, part);
    reduce_part<<<2048, 256, 0, stream>>>(part, vhat);
    mix<<<1024, 256, 0, stream>>>(vhat, wr, wi, xc);
    gemm_inv<<<8192, 256, 0, stream>>>(xc, gt, out);
}

// Round 5
// 344.272 us; speedup vs baseline: 1.1589x; 1.1589x over previous
//
#include <hip/hip_runtime.h>
#include <hip/hip_bf16.h>
#include <hip/hip_fp16.h>
#include <stdint.h>

#define NN 8192
#define NROWS 4096            // B*C = 64*64
#define KSPLIT 2
#define KCHUNK (NN / KSPLIT)  // 4096 per block
#define BM 16                 // rows per block (A-tile)
#define BK 512                // f32 K-elements per staged tile
#define NT (KCHUNK / BK)      // 8 tiles per block
static constexpr float TWO_PI = 6.28318530717958647692f;

typedef __attribute__((ext_vector_type(8))) _Float16 half8;
typedef __attribute__((ext_vector_type(4))) float floatx4;

// async global->LDS, 16B per lane, dest = wave-uniform base + lane*16
#define GLD_LDS(gsrc, ldst)                                                           \
    __builtin_amdgcn_global_load_lds(                                                 \
        (const __attribute__((address_space(1))) uint32_t*)(gsrc),                    \
        (__attribute__((address_space(3))) uint32_t*)(ldst), 16, 0, 0)

// ---------------- twiddle generation (on-device, every launch) -------------------
// btF[j][k], j in [0,128): j<64 -> cos(2pi j k/N); j>=64 -> -sin(2pi (j-64) k/N)
__global__ __launch_bounds__(256) void gen_fwd(_Float16* __restrict__ bt) {
    const int idx = blockIdx.x * 256 + threadIdx.x;   // 128*8192 = 1M
    const int j = idx >> 13;
    const int k = idx & (NN - 1);
    const int m = j & 63;
    const int t = (m * k) & (NN - 1);                 // exact mod-N
    float s, c;
    sincosf((float)t * (TWO_PI / (float)NN), &s, &c);
    bt[idx] = (_Float16)((j < 64) ? c : -s);
}

// gt[n][c], c in [0,128): c<64 -> cos(2pi c n/N); c>=64 -> sin(2pi (c-64) n/N)
__global__ __launch_bounds__(256) void gen_inv(_Float16* __restrict__ gt) {
    const int idx = blockIdx.x * 256 + threadIdx.x;   // 8192*128 = 1M
    const int n = idx >> 7;
    const int c = idx & 127;
    const int m = c & 63;
    const int t = (m * n) & (NN - 1);
    float s, cc;
    sincosf((float)t * (TWO_PI / (float)NN), &s, &cc);
    gt[idx] = (_Float16)((c < 64) ? cc : s);
}

static __device__ inline half8 cvt8(float4 a, float4 b) {
    half8 h;
    h[0] = (_Float16)a.x; h[1] = (_Float16)a.y; h[2] = (_Float16)a.z; h[3] = (_Float16)a.w;
    h[4] = (_Float16)b.x; h[5] = (_Float16)b.y; h[6] = (_Float16)b.z; h[7] = (_Float16)b.w;
    return h;
}

// ---------------- GEMM1: Vhat_partial = v x btF^T --------------------------------
// grid = 256 Mtiles(16 rows) x KSPLIT(2) = 512 blocks (2/CU). A staged once per
// block into double-buffered LDS via async global_load_lds (16B) — HW queue keeps
// a whole 32KB tile in flight (Little's law satisfied); waves j-split (32 cols
// each) and share A via LDS. 16B-granule XOR swizzle (granule ^ (row&7)) applied
// to the GLOBAL source and the LDS READ (linear dest) -> conflict-free ds_read_b128.
__global__ __launch_bounds__(256) void gemm_fwd(const float* __restrict__ v,
                                                const _Float16* __restrict__ bt,
                                                float* __restrict__ part) {
    __shared__ float ldsbuf[2][BM * BK];       // 2 * 32 KiB = 64 KiB
    const int tid  = threadIdx.x;
    const int wid  = tid >> 6;
    const int lane = tid & 63;
    const int l15  = lane & 15;
    const int g    = lane >> 4;                // 0..3 (k-subgroup)
    const int s     = blockIdx.x & (KSPLIT - 1);
    const int mtile = blockIdx.x >> 1;         // 0..255
    const int kbase = s * KCHUNK;

    const int j0 = wid * 32;
    const _Float16* bp0 = bt + (size_t)(j0 + l15) * NN + kbase + g * 8;
    const _Float16* bp1 = bt + (size_t)(j0 + 16 + l15) * NN + kbase + g * 8;

#define STAGE(buf, t)                                                                  \
    {                                                                                  \
        const int k0_ = kbase + (t) * BK;                                              \
        _Pragma("unroll")                                                              \
        for (int c_ = 0; c_ < 4; ++c_) {                                               \
            const int rl_ = wid * 4 + c_;                                              \
            const int h_  = rl_ & 7;                                                   \
            const float* src_ = v + (size_t)(mtile * BM + rl_) * NN + k0_;             \
            float* dst_ = &ldsbuf[(buf)][rl_ * BK];                                    \
            GLD_LDS(src_ + ((lane ^ h_) << 2),       dst_);                            \
            GLD_LDS(src_ + 256 + ((lane ^ h_) << 2), dst_ + 256);                      \
        }                                                                              \
    }

    floatx4 acc0 = {}, acc1 = {};
    const int hh = l15 & 7;

    STAGE(0, 0);
    for (int t = 0; t < NT; ++t) {
        if (t + 1 < NT) STAGE((t + 1) & 1, t + 1);
        __syncthreads();                        // drains staging (vmcnt 0) + sync
        const float* lb = ldsbuf[t & 1];
        #pragma unroll
        for (int ks = 0; ks < 16; ++ks) {
            const int j0g = ks * 8 + g * 2;     // logical 16B-granule index
            float4 x0 = *(const float4*)&lb[l15 * BK + (((j0g)     ^ hh) << 2)];
            float4 x1 = *(const float4*)&lb[l15 * BK + (((j0g + 1) ^ hh) << 2)];
            half8 af = cvt8(x0, x1);
            half8 b0 = *(const half8*)(bp0 + (t) * BK + ks * 32);
            half8 b1 = *(const half8*)(bp1 + (t) * BK + ks * 32);
            acc0 = __builtin_amdgcn_mfma_f32_16x16x32_f16(af, b0, acc0, 0, 0, 0);
            acc1 = __builtin_amdgcn_mfma_f32_16x16x32_f16(af, b1, acc1, 0, 0, 0);
        }
        __syncthreads();                        // protect buffer before next overwrite
    }

    float* pout = part + (size_t)s * NROWS * 128
                + (size_t)(mtile * BM + g * 4) * 128 + j0 + l15;
    #pragma unroll
    for (int r = 0; r < 4; ++r) {
        pout[(size_t)r * 128]      = acc0[r];
        pout[(size_t)r * 128 + 16] = acc1[r];
    }
#undef STAGE
}

// ---------------- reduce K-split partials ----------------------------------------
__global__ __launch_bounds__(256) void reduce_part(const float* __restrict__ part,
                                                   float* __restrict__ vhat) {
    const int idx = blockIdx.x * 256 + threadIdx.x;    // 4096*128 = 512K
    float a = 0.f;
    #pragma unroll
    for (int s = 0; s < KSPLIT; ++s) a += part[(size_t)s * NROWS * 128 + idx];
    vhat[idx] = a;
}

// ---------------- mix: per-frequency complex channel mix + irfft scaling --------
__global__ __launch_bounds__(256) void mix(const float* __restrict__ vhat,
                                           const float* __restrict__ wr,
                                           const float* __restrict__ wi,
                                           _Float16* __restrict__ xc) {
    const int m  = threadIdx.x & 63;
    const int ol = threadIdx.x >> 6;
    const int b  = blockIdx.x >> 4;
    const int o  = ((blockIdx.x & 15) << 2) + ol;

    float ar = 0.f, ai = 0.f;
    #pragma unroll 4
    for (int i = 0; i < 64; ++i) {
        const float* vrow = vhat + (size_t)(b * 64 + i) * 128;
        const float vr = vrow[m];
        const float vi = vrow[64 + m];
        const float wre = wr[((size_t)(i * 64 + o)) * 64 + m];
        const float wim = wi[((size_t)(i * 64 + o)) * 64 + m];
        ar = fmaf(vr, wre, ar);  ar = fmaf(-vi, wim, ar);
        ai = fmaf(vr, wim, ai);  ai = fmaf(vi, wre, ai);
    }
    _Float16* xrow = xc + (size_t)(b * 64 + o) * 128;
    if (m == 0) {
        xrow[0]  = (_Float16)(ar * (1.f / (float)NN));
        xrow[64] = (_Float16)0.f;
    } else {
        xrow[m]      = (_Float16)(ar * (2.f / (float)NN));
        xrow[64 + m] = (_Float16)(-ai * (2.f / (float)NN));
    }
}

// ---------------- GEMM2: out = Xc (4096x128) x G (128x8192) ---------------------
// grid = 128 row-tiles(32 rows) x 32 col-tiles = 4096 blocks; wave owns
// 32 rows x 64 cols as two 16-row groups sharing B-frags (2x B-reuse, 2x ILP).
__global__ __launch_bounds__(256) void gemm_inv(const _Float16* __restrict__ xc,
                                                const _Float16* __restrict__ gt,
                                                float* __restrict__ out) {
    const int wid  = threadIdx.x >> 6;
    const int lane = threadIdx.x & 63;
    const int l15  = lane & 15;
    const int g    = lane >> 4;
    const int mt   = blockIdx.x >> 5;          // 0..127
    const int nt   = blockIdx.x & 31;          // 0..31
    const int row0 = mt * 32;
    const int col0 = nt * 256 + wid * 64;

    half8 a0[4], a1[4];
    const _Float16* ap0 = xc + (size_t)(row0 + l15) * 128 + g * 8;
    const _Float16* ap1 = ap0 + 16 * 128;
    #pragma unroll
    for (int ks = 0; ks < 4; ++ks) {
        a0[ks] = *(const half8*)(ap0 + ks * 32);
        a1[ks] = *(const half8*)(ap1 + ks * 32);
    }

    floatx4 acc0[4] = {}, acc1[4] = {};
    #pragma unroll
    for (int jt = 0; jt < 4; ++jt) {
        const _Float16* gp = gt + (size_t)(col0 + jt * 16 + l15) * 128 + g * 8;
        #pragma unroll
        for (int ks = 0; ks < 4; ++ks) {
            half8 bf = *(const half8*)(gp + ks * 32);
            acc0[jt] = __builtin_amdgcn_mfma_f32_16x16x32_f16(a0[ks], bf, acc0[jt], 0, 0, 0);
            acc1[jt] = __builtin_amdgcn_mfma_f32_16x16x32_f16(a1[ks], bf, acc1[jt], 0, 0, 0);
        }
    }

    #pragma unroll
    for (int jt = 0; jt < 4; ++jt)
        #pragma unroll
        for (int r = 0; r < 4; ++r) {
            out[(size_t)(row0 + g * 4 + r) * NN + col0 + jt * 16 + l15]      = acc0[jt][r];
            out[(size_t)(row0 + 16 + g * 4 + r) * NN + col0 + jt * 16 + l15] = acc1[jt][r];
        }
}

extern "C" void kernel_launch(void* const* d_in, const int* in_sizes, int n_in,
                              void* d_out, int out_size, void* d_ws, size_t ws_size,
                              hipStream_t stream) {
    const float* v  = (const float*)d_in[0];
    const float* wr = (const float*)d_in[1];
    const float* wi = (const float*)d_in[2];
    float* out = (float*)d_out;

    char* ws = (char*)d_ws;
    _Float16* btF  = (_Float16*)(ws);                               // 2 MiB
    _Float16* gt   = (_Float16*)(ws + (2u << 20));                  // 2 MiB
    float*    part = (float*)   (ws + (4u << 20));                  // 4 MiB (16 reserved)
    float*    vhat = (float*)   (ws + (20u << 20));                 // 2 MiB
    _Float16* xc   = (_Float16*)(ws + (22u << 20));                 // 1 MiB

    gen_fwd<<<4096, 256, 0, stream>>>(btF);
    gen_inv<<<4096, 256, 0, stream>>>(gt);
    gemm_fwd<<<256 * KSPLIT, 256, 0, stream>>>(v, btF, part);
    reduce_part<<<2048, 256, 0, stream>>>(part, vhat);
    mix<<<1024, 256, 0, stream>>>(vhat, wr, wi, xc);
    gemm_inv<<<4096, 256, 0, stream>>>(xc, gt, out);
}

// Round 6
// 298.775 us; speedup vs baseline: 1.3354x; 1.1523x over previous
//
#include <hip/hip_runtime.h>
#include <hip/hip_bf16.h>
#include <hip/hip_fp16.h>
#include <stdint.h>

#define NN 8192
#define NROWS 4096             // B*C = 64*64
#define KSPLIT 8
#define KCHUNK (NN / KSPLIT)   // 1024 f32 per block
#define BM 128                 // rows per block
#define BK 64                  // f32 k-elements per phase
#define NPH (KCHUNK / BK)      // 16 phases
static constexpr float TWO_PI = 6.28318530717958647692f;

typedef __attribute__((ext_vector_type(8))) _Float16 half8;
typedef __attribute__((ext_vector_type(4))) float floatx4;

// async global->LDS, 16B/lane; LDS dest = wave-uniform base + lane*16 (linear!)
#define GLD_LDS(gsrc, ldst)                                                           \
    __builtin_amdgcn_global_load_lds(                                                 \
        (const __attribute__((address_space(1))) uint32_t*)(gsrc),                    \
        (__attribute__((address_space(3))) uint32_t*)(ldst), 16, 0, 0)

// ---------------- twiddle generation (on-device, every launch) -------------------
// btF[j][k], j in [0,128): j<64 -> cos(2pi j k/N); j>=64 -> -sin(2pi (j-64) k/N)
__global__ __launch_bounds__(256) void gen_fwd(_Float16* __restrict__ bt) {
    const int idx = blockIdx.x * 256 + threadIdx.x;   // 128*8192 = 1M
    const int j = idx >> 13;
    const int k = idx & (NN - 1);
    const int m = j & 63;
    const int t = (m * k) & (NN - 1);                 // exact mod-N
    float s, c;
    sincosf((float)t * (TWO_PI / (float)NN), &s, &c);
    bt[idx] = (_Float16)((j < 64) ? c : -s);
}

// gt[n][c], c in [0,128): c<64 -> cos(2pi c n/N); c>=64 -> sin(2pi (c-64) n/N)
__global__ __launch_bounds__(256) void gen_inv(_Float16* __restrict__ gt) {
    const int idx = blockIdx.x * 256 + threadIdx.x;   // 8192*128 = 1M
    const int n = idx >> 7;
    const int c = idx & 127;
    const int m = c & 63;
    const int t = (m * n) & (NN - 1);
    float s, cc;
    sincosf((float)t * (TWO_PI / (float)NN), &s, &cc);
    gt[idx] = (_Float16)((c < 64) ? cc : s);
}

static __device__ inline half8 cvt8(float4 a, float4 b) {
    half8 h;
    h[0] = (_Float16)a.x; h[1] = (_Float16)a.y; h[2] = (_Float16)a.z; h[3] = (_Float16)a.w;
    h[4] = (_Float16)b.x; h[5] = (_Float16)b.y; h[6] = (_Float16)b.z; h[7] = (_Float16)b.w;
    return h;
}

// ---------------- GEMM1: Vhat_partial = v x btF^T --------------------------------
// grid = 32 Mtiles(128 rows) x KSPLIT(8) = 256 blocks, 512 thr = 8 waves.
// Counted-vmcnt pipeline (T3+T4): STAGE(t+1) [6 global_load_lds/wave];
// s_waitcnt vmcnt(6) (waits tile t only, leaves t+1 in flight); s_barrier;
// MFMA from LDS; s_barrier. Stage never drains to 0 mid-loop -> overlap.
// Both A (f32) and B=btF (f16) staged; 16B-granule XOR swizzle (granule^(row&7))
// on the GLOBAL source (linear LDS dest) and on the LDS READ -> ~conflict-free.
__global__ __launch_bounds__(512, 2) void gemm_fwd(const float* __restrict__ v,
                                                   const _Float16* __restrict__ bt,
                                                   float* __restrict__ part) {
    __shared__ float    lA[2][BM * BK];      // 2 x 32 KiB
    __shared__ _Float16 lB[2][BM * BK];      // 2 x 16 KiB   (96 KiB total)
    const int tid  = threadIdx.x;
    const int w    = tid >> 6;               // 0..7
    const int lane = tid & 63;
    const int l15  = lane & 15;
    const int g    = lane >> 4;              // 0..3
    const int s     = blockIdx.x & (KSPLIT - 1);
    const int mtile = blockIdx.x >> 3;       // 0..31
    const int kbase = s * KCHUNK;

    const int rA = lane >> 4, cA = lane & 15;  // A stage: 4 rows x 16 granules
    const int rB = lane >> 3, cB = lane & 7;   // B stage: 8 rows x 8 granules

#define STAGE(buf, t)                                                                  \
    {                                                                                  \
        const int kk_ = kbase + (t) * BK;                                              \
        _Pragma("unroll")                                                              \
        for (int i_ = 0; i_ < 4; ++i_) {                                               \
            const int row_ = w * 16 + i_ * 4 + rA;                                     \
            GLD_LDS(v + (size_t)(mtile * BM + row_) * NN + kk_                         \
                      + ((cA ^ (row_ & 7)) << 2),                                      \
                    &lA[buf][(w * 16 + i_ * 4) * BK]);                                 \
        }                                                                              \
        _Pragma("unroll")                                                              \
        for (int i_ = 0; i_ < 2; ++i_) {                                               \
            const int row_ = w * 16 + i_ * 8 + rB;                                     \
            GLD_LDS(bt + (size_t)row_ * NN + kk_ + ((cB ^ (row_ & 7)) << 3),           \
                    &lB[buf][(w * 16 + i_ * 8) * BK]);                                 \
        }                                                                              \
    }

    floatx4 acc[8] = {};
    const int hh = l15 & 7;

    STAGE(0, 0)
    for (int t = 0; t < NPH; ++t) {
        if (t + 1 < NPH) {
            STAGE((t + 1) & 1, t + 1)
            asm volatile("s_waitcnt vmcnt(6)" ::: "memory");   // tile t complete
        } else {
            asm volatile("s_waitcnt vmcnt(0)" ::: "memory");
        }
        __builtin_amdgcn_s_barrier();        // all waves' tile-t staging visible
        const float*    la = lA[t & 1];
        const _Float16* lb = lB[t & 1];
        #pragma unroll
        for (int ks = 0; ks < 2; ++ks) {
            const int ga = ks * 8 + g * 2;   // A granule (16B = 4 f32)
            float4 x0 = *(const float4*)&la[(w * 16 + l15) * BK + (((ga)     ^ hh) << 2)];
            float4 x1 = *(const float4*)&la[(w * 16 + l15) * BK + (((ga + 1) ^ hh) << 2)];
            half8 af = cvt8(x0, x1);
            #pragma unroll
            for (int jt = 0; jt < 8; ++jt) {
                half8 bf = *(const half8*)&lb[(jt * 16 + l15) * BK
                                              + (((ks * 4 + g) ^ hh) << 3)];
                acc[jt] = __builtin_amdgcn_mfma_f32_16x16x32_f16(af, bf, acc[jt], 0, 0, 0);
            }
        }
        __builtin_amdgcn_s_barrier();        // reads done before buf reuse
    }
#undef STAGE

    float* pout = part + (size_t)s * NROWS * 128
                + (size_t)(mtile * BM + w * 16 + g * 4) * 128 + l15;
    #pragma unroll
    for (int jt = 0; jt < 8; ++jt)
        #pragma unroll
        for (int r = 0; r < 4; ++r)
            pout[(size_t)r * 128 + jt * 16] = acc[jt][r];
}

// ---------------- reduce K-split partials ----------------------------------------
__global__ __launch_bounds__(256) void reduce_part(const float* __restrict__ part,
                                                   float* __restrict__ vhat) {
    const int idx = blockIdx.x * 256 + threadIdx.x;    // 4096*128 = 512K
    float a = 0.f;
    #pragma unroll
    for (int s = 0; s < KSPLIT; ++s) a += part[(size_t)s * NROWS * 128 + idx];
    vhat[idx] = a;
}

// ---------------- mix: per-frequency complex channel mix + irfft scaling --------
__global__ __launch_bounds__(256) void mix(const float* __restrict__ vhat,
                                           const float* __restrict__ wr,
                                           const float* __restrict__ wi,
                                           _Float16* __restrict__ xc) {
    const int m  = threadIdx.x & 63;
    const int ol = threadIdx.x >> 6;
    const int b  = blockIdx.x >> 4;
    const int o  = ((blockIdx.x & 15) << 2) + ol;

    float ar = 0.f, ai = 0.f;
    #pragma unroll 4
    for (int i = 0; i < 64; ++i) {
        const float* vrow = vhat + (size_t)(b * 64 + i) * 128;
        const float vr = vrow[m];
        const float vi = vrow[64 + m];
        const float wre = wr[((size_t)(i * 64 + o)) * 64 + m];
        const float wim = wi[((size_t)(i * 64 + o)) * 64 + m];
        ar = fmaf(vr, wre, ar);  ar = fmaf(-vi, wim, ar);
        ai = fmaf(vr, wim, ai);  ai = fmaf(vi, wre, ai);
    }
    _Float16* xrow = xc + (size_t)(b * 64 + o) * 128;
    if (m == 0) {
        xrow[0]  = (_Float16)(ar * (1.f / (float)NN));
        xrow[64] = (_Float16)0.f;
    } else {
        xrow[m]      = (_Float16)(ar * (2.f / (float)NN));
        xrow[64 + m] = (_Float16)(-ai * (2.f / (float)NN));
    }
}

// ---------------- GEMM2: out = Xc (4096x128) x G^T (gt: 8192x128) ----------------
// grid = 16 mt(256 rows) x 32 nt(256 cols) = 512 blocks x 8 waves.
// Wave keeps its 2 B-column-frags in registers for the WHOLE block (gt re-read
// 16x instead of 128x), streams 16-row A-chunks from xc; no LDS, no barriers.
__global__ __launch_bounds__(512, 4) void gemm_inv(const _Float16* __restrict__ xc,
                                                   const _Float16* __restrict__ gt,
                                                   float* __restrict__ out) {
    const int w    = threadIdx.x >> 6;        // 0..7
    const int lane = threadIdx.x & 63;
    const int l15  = lane & 15;
    const int g    = lane >> 4;
    const int mt   = blockIdx.x >> 5;         // 0..15
    const int nt   = blockIdx.x & 31;         // 0..31
    const int col0 = nt * 256 + w * 32;

    half8 bf[2][4];
    #pragma unroll
    for (int jt = 0; jt < 2; ++jt)
        #pragma unroll
        for (int ks = 0; ks < 4; ++ks)
            bf[jt][ks] = *(const half8*)(gt + (size_t)(col0 + jt * 16 + l15) * 128
                                            + ks * 32 + g * 8);

    #pragma unroll 2
    for (int rc = 0; rc < 16; ++rc) {
        const int row0 = mt * 256 + rc * 16;
        const _Float16* ap = xc + (size_t)(row0 + l15) * 128 + g * 8;
        half8 af[4];
        #pragma unroll
        for (int ks = 0; ks < 4; ++ks) af[ks] = *(const half8*)(ap + ks * 32);

        floatx4 a0 = {}, a1 = {};
        #pragma unroll
        for (int ks = 0; ks < 4; ++ks) {
            a0 = __builtin_amdgcn_mfma_f32_16x16x32_f16(af[ks], bf[0][ks], a0, 0, 0, 0);
            a1 = __builtin_amdgcn_mfma_f32_16x16x32_f16(af[ks], bf[1][ks], a1, 0, 0, 0);
        }

        float* op = out + (size_t)(row0 + g * 4) * NN + col0 + l15;
        #pragma unroll
        for (int r = 0; r < 4; ++r) {
            op[(size_t)r * NN]      = a0[r];
            op[(size_t)r * NN + 16] = a1[r];
        }
    }
}

extern "C" void kernel_launch(void* const* d_in, const int* in_sizes, int n_in,
                              void* d_out, int out_size, void* d_ws, size_t ws_size,
                              hipStream_t stream) {
    const float* v  = (const float*)d_in[0];
    const float* wr = (const float*)d_in[1];
    const float* wi = (const float*)d_in[2];
    float* out = (float*)d_out;

    char* ws = (char*)d_ws;
    _Float16* btF  = (_Float16*)(ws);                               // 2 MiB
    _Float16* gt   = (_Float16*)(ws + (2u << 20));                  // 2 MiB
    float*    part = (float*)   (ws + (4u << 20));                  // 16 MiB
    float*    vhat = (float*)   (ws + (20u << 20));                 // 2 MiB
    _Float16* xc   = (_Float16*)(ws + (22u << 20));                 // 1 MiB

    gen_fwd<<<4096, 256, 0, stream>>>(btF);
    gen_inv<<<4096, 256, 0, stream>>>(gt);
    gemm_fwd<<<32 * KSPLIT, 512, 0, stream>>>(v, btF, part);
    reduce_part<<<2048, 256, 0, stream>>>(part, vhat);
    mix<<<1024, 256, 0, stream>>>(vhat, wr, wi, xc);
    gemm_inv<<<512, 512, 0, stream>>>(xc, gt, out);
}